// Round 2
// baseline (758.088 us; speedup 1.0000x reference)
//
#include <hip/hip_runtime.h>
#include <cstdint>
#include <cstddef>

// ---------------- CSR build ----------------

__global__ __launch_bounds__(256) void k_deg_init(int* __restrict__ deg, int n) {
    int i = blockIdx.x * 256 + threadIdx.x;
    if (i < n) deg[i] = 1;  // self-loop
}

__global__ __launch_bounds__(256) void k_deg_count(const int* __restrict__ dstv,
                                                   int* __restrict__ deg, int E) {
    int i = blockIdx.x * 256 + threadIdx.x;
    if (i < E) atomicAdd(&deg[dstv[i]], 1);
}

__global__ __launch_bounds__(256) void k_dinv_bsum(const int* __restrict__ deg,
                                                   float* __restrict__ dinv,
                                                   int* __restrict__ bsum, int n) {
    __shared__ int sred[256];
    int t = threadIdx.x;
    int i = blockIdx.x * 256 + t;
    int d = (i < n) ? deg[i] : 0;
    if (i < n) dinv[i] = rsqrtf((float)d);
    sred[t] = d;
    __syncthreads();
    for (int off = 128; off > 0; off >>= 1) {
        if (t < off) sred[t] += sred[t + off];
        __syncthreads();
    }
    if (t == 0) bsum[blockIdx.x] = sred[0];
}

__global__ __launch_bounds__(1024) void k_scan_bsum(int* __restrict__ bsum, int nb) {
    __shared__ int s[1024];
    int t = threadIdx.x;
    int v = (t < nb) ? bsum[t] : 0;
    s[t] = v;
    __syncthreads();
    for (int off = 1; off < 1024; off <<= 1) {
        int x = 0;
        if (t >= off) x = s[t - off];
        __syncthreads();
        if (t >= off) s[t] += x;
        __syncthreads();
    }
    if (t < nb) bsum[t] = s[t] - v;  // exclusive
}

__global__ __launch_bounds__(256) void k_rowstart(const int* __restrict__ deg,
                                                  const int* __restrict__ bsum,
                                                  int* __restrict__ rowstart,
                                                  int* __restrict__ cursor, int n) {
    __shared__ int s[256];
    int t = threadIdx.x;
    int i = blockIdx.x * 256 + t;
    int d = (i < n) ? deg[i] : 0;
    s[t] = d;
    __syncthreads();
    for (int off = 1; off < 256; off <<= 1) {
        int x = 0;
        if (t >= off) x = s[t - off];
        __syncthreads();
        if (t >= off) s[t] += x;
        __syncthreads();
    }
    int incl = s[t];
    int excl = incl - d;
    int base = bsum[blockIdx.x];
    if (i < n) {
        int rs = base + excl;
        rowstart[i] = rs;
        cursor[i] = rs;
        if (i == n - 1) rowstart[n] = base + incl;
    }
}

__global__ __launch_bounds__(256) void k_fill(const int* __restrict__ srcv,
                                              const int* __restrict__ dstv,
                                              int* __restrict__ cursor,
                                              int* __restrict__ colv, int E, int n) {
    int g = blockIdx.x * 256 + threadIdx.x;
    int total = E + n;
    if (g >= total) return;
    int s, d;
    if (g < E) { s = srcv[g]; d = dstv[g]; }
    else       { s = g - E;   d = s; }
    int pos = atomicAdd(&cursor[d], 1);
    colv[pos] = s;
}

// ---------------- f32 GEMM: C[M][128] = A[M][K] @ Bcat[K][128] ----------------
// Bcat cols 0..63 come from B0 (row stride ldb0), cols 64..127 from B1 (row stride ldb1).
// 128x128 block tile, BK=32, 8x(4+4) microtile per thread, A transposed in LDS.

template<int K>
__global__ __launch_bounds__(256) void gemm128(const float* __restrict__ A,
                                               const float* __restrict__ B0, int ldb0,
                                               const float* __restrict__ B1, int ldb1,
                                               float* __restrict__ C, int M) {
    __shared__ float Ast[32][132];   // [k][row], padded
    __shared__ float Bs[32][128];    // [k][col]
    const int tid = threadIdx.x;
    const int tx = tid & 15;         // 16 col groups (4+4 cols each)
    const int ty = tid >> 4;         // 16 row groups (8 rows each)
    const int r0 = blockIdx.x * 128;

    float4 acc0[8], acc1[8];
#pragma unroll
    for (int m = 0; m < 8; ++m) {
        acc0[m] = make_float4(0.f, 0.f, 0.f, 0.f);
        acc1[m] = make_float4(0.f, 0.f, 0.f, 0.f);
    }

    for (int k0 = 0; k0 < K; k0 += 32) {
        // stage A (128 rows x 32 k), store transposed
#pragma unroll
        for (int p = 0; p < 4; ++p) {
            int flat = (p * 256 + tid) * 4;
            int ar = flat >> 5, ac = flat & 31;
            int grow = r0 + ar;
            float4 v = make_float4(0.f, 0.f, 0.f, 0.f);
            if (grow < M) v = *(const float4*)&A[(size_t)grow * K + k0 + ac];
            Ast[ac + 0][ar] = v.x;
            Ast[ac + 1][ar] = v.y;
            Ast[ac + 2][ar] = v.z;
            Ast[ac + 3][ar] = v.w;
        }
        // stage B (32 k x 128 cols) from two halves
#pragma unroll
        for (int p = 0; p < 4; ++p) {
            int flat = (p * 256 + tid) * 4;
            int br = flat >> 7, bc = flat & 127;
            float4 v;
            if (bc < 64) v = *(const float4*)&B0[(size_t)(k0 + br) * ldb0 + bc];
            else         v = *(const float4*)&B1[(size_t)(k0 + br) * ldb1 + (bc - 64)];
            *(float4*)&Bs[br][bc] = v;
        }
        __syncthreads();

#pragma unroll
        for (int k = 0; k < 32; ++k) {
            float4 a0 = *(const float4*)&Ast[k][ty * 8];
            float4 a1 = *(const float4*)&Ast[k][ty * 8 + 4];
            float4 b0 = *(const float4*)&Bs[k][tx * 4];
            float4 b1 = *(const float4*)&Bs[k][64 + tx * 4];
            const float* av = (const float*)&a0;
#pragma unroll
            for (int m = 0; m < 4; ++m) {
                float am = av[m];
                acc0[m].x += am * b0.x; acc0[m].y += am * b0.y;
                acc0[m].z += am * b0.z; acc0[m].w += am * b0.w;
                acc1[m].x += am * b1.x; acc1[m].y += am * b1.y;
                acc1[m].z += am * b1.z; acc1[m].w += am * b1.w;
            }
            const float* av1 = (const float*)&a1;
#pragma unroll
            for (int m = 0; m < 4; ++m) {
                float am = av1[m];
                acc0[m + 4].x += am * b0.x; acc0[m + 4].y += am * b0.y;
                acc0[m + 4].z += am * b0.z; acc0[m + 4].w += am * b0.w;
                acc1[m + 4].x += am * b1.x; acc1[m + 4].y += am * b1.y;
                acc1[m + 4].z += am * b1.z; acc1[m + 4].w += am * b1.w;
            }
        }
        __syncthreads();
    }

#pragma unroll
    for (int m = 0; m < 8; ++m) {
        int row = r0 + ty * 8 + m;
        if (row < M) {
            *(float4*)&C[(size_t)row * 128 + tx * 4] = acc0[m];
            *(float4*)&C[(size_t)row * 128 + 64 + tx * 4] = acc1[m];
        }
    }
}

// ---------------- prop1: hidden[v] = relu(dinv[v] * sum dinv[c]*h[c] + b1) ----------------

__global__ __launch_bounds__(256) void k_prop1(const float* __restrict__ hsrc,
                                               const int* __restrict__ colv,
                                               const int* __restrict__ rowstart,
                                               const float* __restrict__ dinv,
                                               const float* __restrict__ bias,
                                               float* __restrict__ outb, int n) {
    int wid = (blockIdx.x * 256 + threadIdx.x) >> 6;
    int lane = threadIdx.x & 63;
    if (wid >= n) return;
    int s = rowstart[wid];
    int e = rowstart[wid + 1];
    float ax = 0.f, ay = 0.f;
    int i = s;
    for (; i + 4 <= e; i += 4) {
        int c0 = colv[i], c1 = colv[i + 1], c2 = colv[i + 2], c3 = colv[i + 3];
        float w0 = dinv[c0], w1 = dinv[c1], w2 = dinv[c2], w3 = dinv[c3];
        float2 v0 = *(const float2*)(hsrc + (size_t)c0 * 128 + lane * 2);
        float2 v1 = *(const float2*)(hsrc + (size_t)c1 * 128 + lane * 2);
        float2 v2 = *(const float2*)(hsrc + (size_t)c2 * 128 + lane * 2);
        float2 v3 = *(const float2*)(hsrc + (size_t)c3 * 128 + lane * 2);
        ax += w0 * v0.x + w1 * v1.x + w2 * v2.x + w3 * v3.x;
        ay += w0 * v0.y + w1 * v1.y + w2 * v2.y + w3 * v3.y;
    }
    for (; i < e; ++i) {
        int c = colv[i];
        float w = dinv[c];
        float2 v = *(const float2*)(hsrc + (size_t)c * 128 + lane * 2);
        ax += w * v.x; ay += w * v.y;
    }
    float dv = dinv[wid];
    ax = fmaxf(ax * dv + bias[lane * 2], 0.f);
    ay = fmaxf(ay * dv + bias[lane * 2 + 1], 0.f);
    float2* op = (float2*)(outb + (size_t)wid * 128);
    op[lane] = make_float2(ax, ay);
}

// ---------------- prop2 + fused epilogue ----------------
// P[c] = hidden[c] @ [Wmu|Wls]  (already computed). Aggregate P, then:
// mu = agg[:, :64] + bmu ; ls = agg[:, 64:] + bls ; z = mu + eps*exp(ls)

__global__ __launch_bounds__(256) void k_prop2z(const float* __restrict__ P,
                                                const int* __restrict__ colv,
                                                const int* __restrict__ rowstart,
                                                const float* __restrict__ dinv,
                                                const float* __restrict__ bmu,
                                                const float* __restrict__ bls,
                                                const float* __restrict__ eps,
                                                float* __restrict__ zout,
                                                float* __restrict__ muout,
                                                float* __restrict__ lsout, int n) {
    int wid = (blockIdx.x * 256 + threadIdx.x) >> 6;
    int lane = threadIdx.x & 63;
    if (wid >= n) return;
    int s = rowstart[wid];
    int e = rowstart[wid + 1];
    float ax = 0.f, ay = 0.f;
    int i = s;
    for (; i + 4 <= e; i += 4) {
        int c0 = colv[i], c1 = colv[i + 1], c2 = colv[i + 2], c3 = colv[i + 3];
        float w0 = dinv[c0], w1 = dinv[c1], w2 = dinv[c2], w3 = dinv[c3];
        float2 v0 = *(const float2*)(P + (size_t)c0 * 128 + lane * 2);
        float2 v1 = *(const float2*)(P + (size_t)c1 * 128 + lane * 2);
        float2 v2 = *(const float2*)(P + (size_t)c2 * 128 + lane * 2);
        float2 v3 = *(const float2*)(P + (size_t)c3 * 128 + lane * 2);
        ax += w0 * v0.x + w1 * v1.x + w2 * v2.x + w3 * v3.x;
        ay += w0 * v0.y + w1 * v1.y + w2 * v2.y + w3 * v3.y;
    }
    for (; i < e; ++i) {
        int c = colv[i];
        float w = dinv[c];
        float2 v = *(const float2*)(P + (size_t)c * 128 + lane * 2);
        ax += w * v.x; ay += w * v.y;
    }
    float dv = dinv[wid];
    ax *= dv; ay *= dv;

    int j0 = lane * 2;                 // channel in 0..127
    bool isMu = (lane < 32);
    float b0v = isMu ? bmu[j0] : bls[j0 - 64];
    float b1v = isMu ? bmu[j0 + 1] : bls[j0 - 63];
    float v0 = ax + b0v;
    float v1 = ay + b1v;
    // exp on upper lanes (lower-lane exp unused)
    float e0 = expf(v0), e1 = expf(v1);
    int srcl = (lane & 31) + 32;
    float e0s = __shfl(e0, srcl);
    float e1s = __shfl(e1, srcl);
    if (isMu) {
        float2 ep = *(const float2*)(eps + (size_t)wid * 64 + j0);
        float2 z2 = make_float2(v0 + ep.x * e0s, v1 + ep.y * e1s);
        *(float2*)(zout + (size_t)wid * 64 + j0) = z2;
        *(float2*)(muout + (size_t)wid * 64 + j0) = make_float2(v0, v1);
    } else {
        *(float2*)(lsout + (size_t)wid * 64 + (j0 - 64)) = make_float2(v0, v1);
    }
}

// ---------------- launch ----------------

extern "C" void kernel_launch(void* const* d_in, const int* in_sizes, int n_in,
                              void* d_out, int out_size, void* d_ws, size_t ws_size,
                              hipStream_t stream) {
    const float* x   = (const float*)d_in[0];
    const int*   ei  = (const int*)d_in[1];
    const float* W1  = (const float*)d_in[2];
    const float* b1  = (const float*)d_in[3];
    const float* Wmu = (const float*)d_in[4];
    const float* bmu = (const float*)d_in[5];
    const float* Wls = (const float*)d_in[6];
    const float* bls = (const float*)d_in[7];
    const float* eps = (const float*)d_in[8];

    const int n = in_sizes[0] / 256;   // 100000
    const int E = in_sizes[1] / 2;     // 1600000
    const int* srcv = ei;
    const int* dstv = ei + E;

    char* w = (char*)d_ws;
    auto alloc = [&](size_t bytes) -> char* {
        char* p = w;
        w += (bytes + 255) & ~(size_t)255;
        return p;
    };
    int*   deg      = (int*)alloc((size_t)n * 4);
    float* dinv     = (float*)alloc((size_t)n * 4);
    int*   rowstart = (int*)alloc((size_t)(n + 1) * 4);
    int*   cursor   = (int*)alloc((size_t)n * 4);
    int*   bsum     = (int*)alloc(4096);
    int*   colv     = (int*)alloc((size_t)(E + n) * 4);
    float* h        = (float*)alloc((size_t)n * 128 * 4);   // x@W1, later reused as P
    float* hidden   = (float*)alloc((size_t)n * 128 * 4);
    float* P        = h;  // h is dead after prop1; P = hidden@[Wmu|Wls] overwrites it

    const int nb = (n + 255) / 256;

    k_deg_init<<<nb, 256, 0, stream>>>(deg, n);
    k_deg_count<<<(E + 255) / 256, 256, 0, stream>>>(dstv, deg, E);
    k_dinv_bsum<<<nb, 256, 0, stream>>>(deg, dinv, bsum, n);
    k_scan_bsum<<<1, 1024, 0, stream>>>(bsum, nb);
    k_rowstart<<<nb, 256, 0, stream>>>(deg, bsum, rowstart, cursor, n);
    k_fill<<<(E + n + 255) / 256, 256, 0, stream>>>(srcv, dstv, cursor, colv, E, n);

    // h = x @ W1   (K=256, Bcat halves both from W1)
    gemm128<256><<<(n + 127) / 128, 256, 0, stream>>>(x, W1, 128, W1 + 64, 128, h, n);
    // hidden = relu(Ahat*h + b1)
    k_prop1<<<(n + 3) / 4, 256, 0, stream>>>(h, colv, rowstart, dinv, b1, hidden, n);
    // P = hidden @ [Wmu | Wls]   (K=128)
    gemm128<128><<<(n + 127) / 128, 256, 0, stream>>>(hidden, Wmu, 64, Wls, 64, P, n);

    float* zout  = (float*)d_out;
    float* muout = zout + (size_t)n * 64;
    float* lsout = muout + (size_t)n * 64;
    // agg = Ahat*P ; mu/ls/z epilogue fused
    k_prop2z<<<(n + 3) / 4, 256, 0, stream>>>(P, colv, rowstart, dinv, bmu, bls, eps,
                                              zout, muout, lsout, n);
}

// Round 3
// 591.488 us; speedup vs baseline: 1.2817x; 1.2817x over previous
//
#include <hip/hip_runtime.h>
#include <cstdint>
#include <cstddef>

typedef __attribute__((ext_vector_type(8))) short short8v;   // 8 bf16 in 4 VGPRs
typedef __attribute__((ext_vector_type(4))) float f32x4;

__device__ __forceinline__ unsigned short f2bf_rne(float x) {
    unsigned int u = __float_as_uint(x);
    return (unsigned short)((u + 0x7fffu + ((u >> 16) & 1u)) >> 16);
}
__device__ __forceinline__ float bf2f(unsigned short h) {
    return __uint_as_float(((unsigned int)h) << 16);
}

// ---------------- CSR build ----------------

__global__ __launch_bounds__(256) void k_deg_init(int* __restrict__ deg, int n) {
    int i = blockIdx.x * 256 + threadIdx.x;
    if (i < n) deg[i] = 1;  // self-loop
}

__global__ __launch_bounds__(256) void k_deg_count(const int* __restrict__ dstv,
                                                   int* __restrict__ deg, int E) {
    int i = blockIdx.x * 256 + threadIdx.x;
    if (i < E) atomicAdd(&deg[dstv[i]], 1);
}

__global__ __launch_bounds__(256) void k_dinv_bsum(const int* __restrict__ deg,
                                                   float* __restrict__ dinv,
                                                   int* __restrict__ bsum, int n) {
    __shared__ int sred[256];
    int t = threadIdx.x;
    int i = blockIdx.x * 256 + t;
    int d = (i < n) ? deg[i] : 0;
    if (i < n) dinv[i] = rsqrtf((float)d);
    sred[t] = d;
    __syncthreads();
    for (int off = 128; off > 0; off >>= 1) {
        if (t < off) sred[t] += sred[t + off];
        __syncthreads();
    }
    if (t == 0) bsum[blockIdx.x] = sred[0];
}

__global__ __launch_bounds__(1024) void k_scan_bsum(int* __restrict__ bsum, int nb) {
    __shared__ int s[1024];
    int t = threadIdx.x;
    int v = (t < nb) ? bsum[t] : 0;
    s[t] = v;
    __syncthreads();
    for (int off = 1; off < 1024; off <<= 1) {
        int x = 0;
        if (t >= off) x = s[t - off];
        __syncthreads();
        if (t >= off) s[t] += x;
        __syncthreads();
    }
    if (t < nb) bsum[t] = s[t] - v;  // exclusive
}

__global__ __launch_bounds__(256) void k_rowstart(const int* __restrict__ deg,
                                                  const int* __restrict__ bsum,
                                                  int* __restrict__ rowstart,
                                                  int* __restrict__ cursor, int n) {
    __shared__ int s[256];
    int t = threadIdx.x;
    int i = blockIdx.x * 256 + t;
    int d = (i < n) ? deg[i] : 0;
    s[t] = d;
    __syncthreads();
    for (int off = 1; off < 256; off <<= 1) {
        int x = 0;
        if (t >= off) x = s[t - off];
        __syncthreads();
        if (t >= off) s[t] += x;
        __syncthreads();
    }
    int incl = s[t];
    int excl = incl - d;
    int base = bsum[blockIdx.x];
    if (i < n) {
        int rs = base + excl;
        rowstart[i] = rs;
        cursor[i] = rs;
        if (i == n - 1) rowstart[n] = base + incl;
    }
}

__global__ __launch_bounds__(256) void k_fill(const int* __restrict__ srcv,
                                              const int* __restrict__ dstv,
                                              int* __restrict__ cursor,
                                              int* __restrict__ colv, int E, int n) {
    int g = blockIdx.x * 256 + threadIdx.x;
    int total = E + n;
    if (g >= total) return;
    int s, d;
    if (g < E) { s = srcv[g]; d = dstv[g]; }
    else       { s = g - E;   d = s; }
    int pos = atomicAdd(&cursor[d], 1);
    colv[pos] = s;
}

// ---------------- weight prep: split f32 -> bf16 hi/lo, transposed [col][K] ----------------

__global__ __launch_bounds__(256) void k_prepB(const float* __restrict__ W1,
                                               const float* __restrict__ Wmu,
                                               const float* __restrict__ Wls,
                                               unsigned short* __restrict__ B1h,
                                               unsigned short* __restrict__ B1l,
                                               unsigned short* __restrict__ B2h,
                                               unsigned short* __restrict__ B2l) {
    int i = blockIdx.x * 256 + threadIdx.x;
    if (i < 256 * 128) {               // W1 [256][128] -> B1[c][k], K=256
        int k = i >> 7, c = i & 127;
        float v = W1[i];
        unsigned short h = f2bf_rne(v);
        float r = v - bf2f(h);
        B1h[c * 256 + k] = h;
        B1l[c * 256 + k] = f2bf_rne(r);
    }
    if (i < 128 * 128) {               // [Wmu|Wls] [128][128] -> B2[c][k], K=128
        int k = i >> 7, c = i & 127;
        float v = (c < 64) ? Wmu[k * 64 + c] : Wls[k * 64 + (c - 64)];
        unsigned short h = f2bf_rne(v);
        float r = v - bf2f(h);
        B2h[c * 128 + k] = h;
        B2l[c * 128 + k] = f2bf_rne(r);
    }
}

// ---------------- MFMA split-bf16 GEMM: C[M][128] = dinv[row] * (A[M][K] @ B[K][128]) ----------------
// No LDS, no barriers. Wave = 32 rows x 128 cols. A frags converted in-register,
// B frags loaded from pre-split transposed bf16 [col][K] (L2-hot).

template<int K>
__global__ __launch_bounds__(256) void k_gemm_split(const float* __restrict__ A,
                                                    const unsigned short* __restrict__ Bth,
                                                    const unsigned short* __restrict__ Btl,
                                                    const float* __restrict__ dinv,
                                                    float* __restrict__ C, int M) {
    const int tid = threadIdx.x;
    const int wv = tid >> 6;
    const int l = tid & 63;
    const int lr = l & 15;         // row-in-tile (A) / col-in-tile (B,C)
    const int lk = (l >> 4) * 8;   // k offset within 32-k step
    const int row0 = blockIdx.x * 128 + wv * 32;

    f32x4 acc[2][8];
#pragma unroll
    for (int rt = 0; rt < 2; ++rt)
#pragma unroll
        for (int ct = 0; ct < 8; ++ct) acc[rt][ct] = (f32x4){0.f, 0.f, 0.f, 0.f};

    int r0g = row0 + lr, r1g = row0 + 16 + lr;
    const float* a0p = A + (size_t)(r0g < M ? r0g : 0) * K;  // clamp: garbage rows never stored
    const float* a1p = A + (size_t)(r1g < M ? r1g : 0) * K;

    for (int k0 = 0; k0 < K; k0 += 32) {
        short8v ah[2], al[2];
#pragma unroll
        for (int rt = 0; rt < 2; ++rt) {
            const float* ap = rt ? a1p : a0p;
            float4 fa = *(const float4*)(ap + k0 + lk);
            float4 fb = *(const float4*)(ap + k0 + lk + 4);
            float av[8] = {fa.x, fa.y, fa.z, fa.w, fb.x, fb.y, fb.z, fb.w};
#pragma unroll
            for (int q = 0; q < 8; ++q) {
                unsigned short h = f2bf_rne(av[q]);
                float r = av[q] - bf2f(h);
                ah[rt][q] = (short)h;
                al[rt][q] = (short)f2bf_rne(r);
            }
        }
#pragma unroll
        for (int ct = 0; ct < 8; ++ct) {
            const size_t bo = (size_t)(ct * 16 + lr) * K + k0 + lk;
            short8v bh = *(const short8v*)(Bth + bo);
            short8v bl = *(const short8v*)(Btl + bo);
#pragma unroll
            for (int rt = 0; rt < 2; ++rt) {
                acc[rt][ct] = __builtin_amdgcn_mfma_f32_16x16x32_bf16(ah[rt], bh, acc[rt][ct], 0, 0, 0);
                acc[rt][ct] = __builtin_amdgcn_mfma_f32_16x16x32_bf16(al[rt], bh, acc[rt][ct], 0, 0, 0);
                acc[rt][ct] = __builtin_amdgcn_mfma_f32_16x16x32_bf16(ah[rt], bl, acc[rt][ct], 0, 0, 0);
            }
        }
    }

    // C/D layout (verified): col = lane&15, row = (lane>>4)*4 + reg
#pragma unroll
    for (int rt = 0; rt < 2; ++rt) {
        int rbase = row0 + rt * 16 + ((l >> 4) << 2);
#pragma unroll
        for (int j = 0; j < 4; ++j) {
            int row = rbase + j;
            if (row < M) {
                float dv = dinv[row];
#pragma unroll
                for (int ct = 0; ct < 8; ++ct)
                    C[(size_t)row * 128 + ct * 16 + lr] = dv * acc[rt][ct][j];
            }
        }
    }
}

// ---------------- prop1: hidden[v] = relu(dinv[v] * sum_{c} h'[c] + b1) ----------------
// h' rows already scaled by dinv. Wave = 1 node, 2 edges in parallel (32 lanes x float4 each).

__global__ __launch_bounds__(256) void k_prop1(const float* __restrict__ hsrc,
                                               const int* __restrict__ colv,
                                               const int* __restrict__ rowstart,
                                               const float* __restrict__ dinv,
                                               const float* __restrict__ bias,
                                               float* __restrict__ outb, int n) {
    int wid = (blockIdx.x * 256 + threadIdx.x) >> 6;
    if (wid >= n) return;
    int lane = threadIdx.x & 63;
    int half = lane >> 5;
    int cl = lane & 31;            // channel group: floats cl*4..cl*4+3
    int s = rowstart[wid];
    int cnt = rowstart[wid + 1] - s;
    float ax = 0.f, ay = 0.f, az = 0.f, aw = 0.f;
    int i = 0;
    for (; i + 8 <= cnt; i += 8) {
        int c0 = colv[s + i + half];
        int c1 = colv[s + i + 2 + half];
        int c2 = colv[s + i + 4 + half];
        int c3 = colv[s + i + 6 + half];
        float4 v0 = *(const float4*)(hsrc + (size_t)c0 * 128 + cl * 4);
        float4 v1 = *(const float4*)(hsrc + (size_t)c1 * 128 + cl * 4);
        float4 v2 = *(const float4*)(hsrc + (size_t)c2 * 128 + cl * 4);
        float4 v3 = *(const float4*)(hsrc + (size_t)c3 * 128 + cl * 4);
        ax += v0.x + v1.x + v2.x + v3.x;
        ay += v0.y + v1.y + v2.y + v3.y;
        az += v0.z + v1.z + v2.z + v3.z;
        aw += v0.w + v1.w + v2.w + v3.w;
    }
    for (; i + 2 <= cnt; i += 2) {
        int c = colv[s + i + half];
        float4 v = *(const float4*)(hsrc + (size_t)c * 128 + cl * 4);
        ax += v.x; ay += v.y; az += v.z; aw += v.w;
    }
    if (i < cnt && half == 0) {
        int c = colv[s + i];
        float4 v = *(const float4*)(hsrc + (size_t)c * 128 + cl * 4);
        ax += v.x; ay += v.y; az += v.z; aw += v.w;
    }
    ax += __shfl_xor(ax, 32);
    ay += __shfl_xor(ay, 32);
    az += __shfl_xor(az, 32);
    aw += __shfl_xor(aw, 32);
    if (half == 0) {
        float dv = dinv[wid];
        float4 b = *(const float4*)(bias + cl * 4);
        float4 o;
        o.x = fmaxf(ax * dv + b.x, 0.f);
        o.y = fmaxf(ay * dv + b.y, 0.f);
        o.z = fmaxf(az * dv + b.z, 0.f);
        o.w = fmaxf(aw * dv + b.w, 0.f);
        *(float4*)(outb + (size_t)wid * 128 + cl * 4) = o;
    }
}

// ---------------- prop2 + fused epilogue ----------------
// P' rows already scaled by dinv. agg = sum P'[c]; val = agg*dinv[v] + [bmu|bls];
// z = mu + eps*exp(ls)

__global__ __launch_bounds__(256) void k_prop2z(const float* __restrict__ P,
                                                const int* __restrict__ colv,
                                                const int* __restrict__ rowstart,
                                                const float* __restrict__ dinv,
                                                const float* __restrict__ bmu,
                                                const float* __restrict__ bls,
                                                const float* __restrict__ eps,
                                                float* __restrict__ zout,
                                                float* __restrict__ muout,
                                                float* __restrict__ lsout, int n) {
    int wid = (blockIdx.x * 256 + threadIdx.x) >> 6;
    if (wid >= n) return;
    int lane = threadIdx.x & 63;
    int half = lane >> 5;
    int cl = lane & 31;
    int s = rowstart[wid];
    int cnt = rowstart[wid + 1] - s;
    float ax = 0.f, ay = 0.f, az = 0.f, aw = 0.f;
    int i = 0;
    for (; i + 8 <= cnt; i += 8) {
        int c0 = colv[s + i + half];
        int c1 = colv[s + i + 2 + half];
        int c2 = colv[s + i + 4 + half];
        int c3 = colv[s + i + 6 + half];
        float4 v0 = *(const float4*)(P + (size_t)c0 * 128 + cl * 4);
        float4 v1 = *(const float4*)(P + (size_t)c1 * 128 + cl * 4);
        float4 v2 = *(const float4*)(P + (size_t)c2 * 128 + cl * 4);
        float4 v3 = *(const float4*)(P + (size_t)c3 * 128 + cl * 4);
        ax += v0.x + v1.x + v2.x + v3.x;
        ay += v0.y + v1.y + v2.y + v3.y;
        az += v0.z + v1.z + v2.z + v3.z;
        aw += v0.w + v1.w + v2.w + v3.w;
    }
    for (; i + 2 <= cnt; i += 2) {
        int c = colv[s + i + half];
        float4 v = *(const float4*)(P + (size_t)c * 128 + cl * 4);
        ax += v.x; ay += v.y; az += v.z; aw += v.w;
    }
    if (i < cnt && half == 0) {
        int c = colv[s + i];
        float4 v = *(const float4*)(P + (size_t)c * 128 + cl * 4);
        ax += v.x; ay += v.y; az += v.z; aw += v.w;
    }
    ax += __shfl_xor(ax, 32);
    ay += __shfl_xor(ay, 32);
    az += __shfl_xor(az, 32);
    aw += __shfl_xor(aw, 32);

    float dv = dinv[wid];
    int ch0 = cl * 4;  // 0..124 ; cl<16 -> mu channels, cl>=16 -> ls channels
    float4 bb;
    if (cl < 16) bb = *(const float4*)(bmu + ch0);
    else         bb = *(const float4*)(bls + (ch0 - 64));
    float4 val;
    val.x = ax * dv + bb.x;
    val.y = ay * dv + bb.y;
    val.z = az * dv + bb.z;
    val.w = aw * dv + bb.w;
    float4 ex;
    ex.x = __expf(val.x); ex.y = __expf(val.y);
    ex.z = __expf(val.z); ex.w = __expf(val.w);
    float4 exs;
    exs.x = __shfl(ex.x, lane + 16);
    exs.y = __shfl(ex.y, lane + 16);
    exs.z = __shfl(ex.z, lane + 16);
    exs.w = __shfl(ex.w, lane + 16);
    if (half == 0) {
        if (cl < 16) {
            float4 ep = *(const float4*)(eps + (size_t)wid * 64 + ch0);
            float4 z;
            z.x = val.x + ep.x * exs.x;
            z.y = val.y + ep.y * exs.y;
            z.z = val.z + ep.z * exs.z;
            z.w = val.w + ep.w * exs.w;
            *(float4*)(zout + (size_t)wid * 64 + ch0) = z;
            *(float4*)(muout + (size_t)wid * 64 + ch0) = val;
        } else {
            *(float4*)(lsout + (size_t)wid * 64 + (ch0 - 64)) = val;
        }
    }
}

// ---------------- launch ----------------

extern "C" void kernel_launch(void* const* d_in, const int* in_sizes, int n_in,
                              void* d_out, int out_size, void* d_ws, size_t ws_size,
                              hipStream_t stream) {
    const float* x   = (const float*)d_in[0];
    const int*   ei  = (const int*)d_in[1];
    const float* W1  = (const float*)d_in[2];
    const float* b1  = (const float*)d_in[3];
    const float* Wmu = (const float*)d_in[4];
    const float* bmu = (const float*)d_in[5];
    const float* Wls = (const float*)d_in[6];
    const float* bls = (const float*)d_in[7];
    const float* eps = (const float*)d_in[8];

    const int n = in_sizes[0] / 256;   // 100000
    const int E = in_sizes[1] / 2;     // 1600000
    const int* srcv = ei;
    const int* dstv = ei + E;

    char* w = (char*)d_ws;
    auto alloc = [&](size_t bytes) -> char* {
        char* p = w;
        w += (bytes + 255) & ~(size_t)255;
        return p;
    };
    int*   deg      = (int*)alloc((size_t)n * 4);
    float* dinv     = (float*)alloc((size_t)n * 4);
    int*   rowstart = (int*)alloc((size_t)(n + 1) * 4);
    int*   cursor   = (int*)alloc((size_t)n * 4);
    int*   bsum     = (int*)alloc(4096);
    int*   colv     = (int*)alloc((size_t)(E + n) * 4);
    unsigned short* B1h = (unsigned short*)alloc(128 * 256 * 2);
    unsigned short* B1l = (unsigned short*)alloc(128 * 256 * 2);
    unsigned short* B2h = (unsigned short*)alloc(128 * 128 * 2);
    unsigned short* B2l = (unsigned short*)alloc(128 * 128 * 2);
    float* h        = (float*)alloc((size_t)n * 128 * 4);   // x@W1 (dinv-scaled), reused as P
    float* hidden   = (float*)alloc((size_t)n * 128 * 4);
    float* P        = h;

    const int nb = (n + 255) / 256;

    k_deg_init<<<nb, 256, 0, stream>>>(deg, n);
    k_deg_count<<<(E + 255) / 256, 256, 0, stream>>>(dstv, deg, E);
    k_dinv_bsum<<<nb, 256, 0, stream>>>(deg, dinv, bsum, n);
    k_scan_bsum<<<1, 1024, 0, stream>>>(bsum, nb);
    k_rowstart<<<nb, 256, 0, stream>>>(deg, bsum, rowstart, cursor, n);
    k_fill<<<(E + n + 255) / 256, 256, 0, stream>>>(srcv, dstv, cursor, colv, E, n);
    k_prepB<<<128, 256, 0, stream>>>(W1, Wmu, Wls, B1h, B1l, B2h, B2l);

    // h' = dinv .* (x @ W1)
    k_gemm_split<256><<<(n + 127) / 128, 256, 0, stream>>>(x, B1h, B1l, dinv, h, n);
    // hidden = relu(dinv[v] * sum h'[c] + b1)
    k_prop1<<<(n + 3) / 4, 256, 0, stream>>>(h, colv, rowstart, dinv, b1, hidden, n);
    // P' = dinv .* (hidden @ [Wmu|Wls])
    k_gemm_split<128><<<(n + 127) / 128, 256, 0, stream>>>(hidden, B2h, B2l, dinv, P, n);

    float* zout  = (float*)d_out;
    float* muout = zout + (size_t)n * 64;
    float* lsout = muout + (size_t)n * 64;
    k_prop2z<<<(n + 3) / 4, 256, 0, stream>>>(P, colv, rowstart, dinv, bmu, bls, eps,
                                              zout, muout, lsout, n);
}

// Round 4
// 349.444 us; speedup vs baseline: 2.1694x; 1.6927x over previous
//
#include <hip/hip_runtime.h>
#include <cstdint>
#include <cstddef>

typedef __attribute__((ext_vector_type(8))) short short8v;   // 8 bf16 / 4 VGPRs
typedef __attribute__((ext_vector_type(4))) float f32x4;

#define BSHIFT 9            // 512 nodes per bucket
#define NBUCK_MAX 256

__device__ __forceinline__ unsigned short f2bf_rne(float x) {
    unsigned int u = __float_as_uint(x);
    return (unsigned short)((u + 0x7fffu + ((u >> 16) & 1u)) >> 16);
}
__device__ __forceinline__ float bf2f(unsigned short h) {
    return __uint_as_float(((unsigned int)h) << 16);
}
__device__ __forceinline__ float bflo(unsigned int u) { return __uint_as_float(u << 16); }
__device__ __forceinline__ float bfhi(unsigned int u) { return __uint_as_float(u & 0xffff0000u); }

__device__ __forceinline__ void acc8(float* a, uint4 v) {
    a[0] += bflo(v.x); a[1] += bfhi(v.x);
    a[2] += bflo(v.y); a[3] += bfhi(v.y);
    a[4] += bflo(v.z); a[5] += bfhi(v.z);
    a[6] += bflo(v.w); a[7] += bfhi(v.w);
}

// ---------------- CSR build: bucketed (512 nodes/bucket) ----------------

// Pass A: global bucket histogram (gcnt must be pre-zeroed)
__global__ __launch_bounds__(256) void k_hist(const int* __restrict__ dstv,
                                              int* __restrict__ gcnt, int E) {
    __shared__ int h[NBUCK_MAX];
    int t = threadIdx.x;
    for (int b = t; b < NBUCK_MAX; b += 256) h[b] = 0;
    __syncthreads();
    int base = blockIdx.x * 4096;
    for (int q = 0; q < 16; ++q) {
        int i = base + q * 256 + t;
        if (i < E) atomicAdd(&h[dstv[i] >> BSHIFT], 1);
    }
    __syncthreads();
    for (int b = t; b < NBUCK_MAX; b += 256)
        if (h[b]) atomicAdd(&gcnt[b], h[b]);
}

// Pass B: exclusive scan of bucket counts -> bstart, bcur
__global__ __launch_bounds__(256) void k_scanb(const int* __restrict__ gcnt,
                                               int* __restrict__ bstart,
                                               int* __restrict__ bcur, int nbuck, int E) {
    __shared__ int s[256];
    int t = threadIdx.x;
    int v = (t < nbuck) ? gcnt[t] : 0;
    s[t] = v;
    __syncthreads();
    for (int off = 1; off < 256; off <<= 1) {
        int x = 0;
        if (t >= off) x = s[t - off];
        __syncthreads();
        if (t >= off) s[t] += x;
        __syncthreads();
    }
    if (t < nbuck) { int ex = s[t] - v; bstart[t] = ex; bcur[t] = ex; }
    if (t == 0) bstart[nbuck] = E;
}

// Pass C: scatter packed (src,dst) into bucket segments (block-local binning)
__global__ __launch_bounds__(256) void k_scatb(const int* __restrict__ srcv,
                                               const int* __restrict__ dstv,
                                               int* __restrict__ bcur,
                                               unsigned long long* __restrict__ ebuf, int E) {
    __shared__ int hcnt[NBUCK_MAX], hbase[NBUCK_MAX], hcur[NBUCK_MAX];
    int t = threadIdx.x;
    for (int b = t; b < NBUCK_MAX; b += 256) { hcnt[b] = 0; hcur[b] = 0; }
    __syncthreads();
    int base = blockIdx.x * 4096;
    for (int q = 0; q < 16; ++q) {
        int i = base + q * 256 + t;
        if (i < E) atomicAdd(&hcnt[dstv[i] >> BSHIFT], 1);
    }
    __syncthreads();
    for (int b = t; b < NBUCK_MAX; b += 256)
        hbase[b] = hcnt[b] ? atomicAdd(&bcur[b], hcnt[b]) : 0;
    __syncthreads();
    for (int q = 0; q < 16; ++q) {
        int i = base + q * 256 + t;
        if (i < E) {
            int d = dstv[i], b = d >> BSHIFT;
            int off = atomicAdd(&hcur[b], 1);
            ebuf[hbase[b] + off] =
                (unsigned long long)(unsigned)srcv[i] | ((unsigned long long)(unsigned)d << 32);
        }
    }
}

// Pass D: per-bucket counting sort -> colv, rowstart, dinv
__global__ __launch_bounds__(512) void k_bsort(const unsigned long long* __restrict__ ebuf,
                                               const int* __restrict__ bstart,
                                               int* __restrict__ colv,
                                               int* __restrict__ rowstart,
                                               float* __restrict__ dinv,
                                               int n, int nbuck, int E) {
    __shared__ int cnt[512], sc[512], cur[512];
    int t = threadIdx.x;
    int b = blockIdx.x;
    int node0 = b << BSHIFT;
    int nn = min(512, n - node0);
    cnt[t] = 0;
    __syncthreads();
    int s0 = bstart[b], e0 = bstart[b + 1];
    for (int i = s0 + t; i < e0; i += 512) {
        int d = (int)(ebuf[i] >> 32);
        atomicAdd(&cnt[d - node0], 1);
    }
    __syncthreads();
    int v = cnt[t];
    sc[t] = v;
    __syncthreads();
    for (int off = 1; off < 512; off <<= 1) {
        int x = 0;
        if (t >= off) x = sc[t - off];
        __syncthreads();
        if (t >= off) sc[t] += x;
        __syncthreads();
    }
    if (t < nn) {
        int rs = s0 + sc[t] - v;
        cur[t] = rs;
        rowstart[node0 + t] = rs;
        dinv[node0 + t] = rsqrtf((float)(v + 1));   // +1 self-loop
    }
    if (b == nbuck - 1 && t == 0) rowstart[n] = E;
    __syncthreads();
    for (int i = s0 + t; i < e0; i += 512) {
        unsigned long long pv = ebuf[i];
        int d = (int)(pv >> 32);
        int pos = atomicAdd(&cur[d - node0], 1);
        colv[pos] = (int)(unsigned)(pv & 0xffffffffu);
    }
}

// ---------------- weight prep: split f32 -> bf16 hi/lo, transposed [mfma_col][K] ----------------
// MFMA col c maps to actual output channel ch(c) = (c&15)*8 + (c>>4), so each lane
// (lr = lane&15) ends up owning 8 contiguous channels lr*8..lr*8+7 -> packed stores.

__global__ __launch_bounds__(256) void k_prepB(const float* __restrict__ W1,
                                               const float* __restrict__ Wmu,
                                               const float* __restrict__ Wls,
                                               unsigned short* __restrict__ B1h,
                                               unsigned short* __restrict__ B1l,
                                               unsigned short* __restrict__ B2h,
                                               unsigned short* __restrict__ B2l) {
    int i = blockIdx.x * 256 + threadIdx.x;
    if (i < 256 * 128) {               // W1 [256][128]
        int k = i >> 7, c = i & 127;
        int ch = ((c & 15) << 3) | (c >> 4);
        float vv = W1[k * 128 + ch];
        unsigned short h = f2bf_rne(vv);
        B1h[c * 256 + k] = h;
        B1l[c * 256 + k] = f2bf_rne(vv - bf2f(h));
    }
    if (i < 128 * 128) {               // [Wmu|Wls] [128][128]
        int k = i >> 7, c = i & 127;
        int ch = ((c & 15) << 3) | (c >> 4);
        float vv = (ch < 64) ? Wmu[k * 64 + ch] : Wls[k * 64 + (ch - 64)];
        unsigned short h = f2bf_rne(vv);
        B2h[c * 128 + k] = h;
        B2l[c * 128 + k] = f2bf_rne(vv - bf2f(h));
    }
}

// ---------------- GEMM1: h' = dinv .* (x @ W1), out bf16 [n][128] ----------------
// f32 A split hi/lo (3 MFMA), no LDS/barriers; wave = 32 rows x 128 cols.

__global__ __launch_bounds__(256) void k_gemm1(const float* __restrict__ A,
                                               const unsigned short* __restrict__ Bth,
                                               const unsigned short* __restrict__ Btl,
                                               const float* __restrict__ dinv,
                                               unsigned short* __restrict__ Cb, int M) {
    const int K = 256;
    const int tid = threadIdx.x;
    const int wv = tid >> 6, l = tid & 63;
    const int lr = l & 15, lk = (l >> 4) * 8;
    const int row0 = blockIdx.x * 128 + wv * 32;

    f32x4 acc[2][8];
#pragma unroll
    for (int rt = 0; rt < 2; ++rt)
#pragma unroll
        for (int ct = 0; ct < 8; ++ct) acc[rt][ct] = (f32x4){0.f, 0.f, 0.f, 0.f};

    int r0g = row0 + lr, r1g = row0 + 16 + lr;
    const float* a0p = A + (size_t)(r0g < M ? r0g : 0) * K;
    const float* a1p = A + (size_t)(r1g < M ? r1g : 0) * K;

    for (int k0 = 0; k0 < K; k0 += 32) {
        short8v ah[2], al[2];
#pragma unroll
        for (int rt = 0; rt < 2; ++rt) {
            const float* ap = rt ? a1p : a0p;
            float4 fa = *(const float4*)(ap + k0 + lk);
            float4 fb = *(const float4*)(ap + k0 + lk + 4);
            float av[8] = {fa.x, fa.y, fa.z, fa.w, fb.x, fb.y, fb.z, fb.w};
#pragma unroll
            for (int q = 0; q < 8; ++q) {
                unsigned short h = f2bf_rne(av[q]);
                ah[rt][q] = (short)h;
                al[rt][q] = (short)f2bf_rne(av[q] - bf2f(h));
            }
        }
#pragma unroll
        for (int ct = 0; ct < 8; ++ct) {
            const size_t bo = (size_t)(ct * 16 + lr) * K + k0 + lk;
            short8v bh = *(const short8v*)(Bth + bo);
            short8v bl = *(const short8v*)(Btl + bo);
#pragma unroll
            for (int rt = 0; rt < 2; ++rt) {
                acc[rt][ct] = __builtin_amdgcn_mfma_f32_16x16x32_bf16(ah[rt], bh, acc[rt][ct], 0, 0, 0);
                acc[rt][ct] = __builtin_amdgcn_mfma_f32_16x16x32_bf16(al[rt], bh, acc[rt][ct], 0, 0, 0);
                acc[rt][ct] = __builtin_amdgcn_mfma_f32_16x16x32_bf16(ah[rt], bl, acc[rt][ct], 0, 0, 0);
            }
        }
    }

    // C/D: col = lane&15 (=lr), row = (lane>>4)*4 + j ; lane owns channels lr*8+ct
#pragma unroll
    for (int rt = 0; rt < 2; ++rt) {
        int rbase = row0 + rt * 16 + ((l >> 4) << 2);
#pragma unroll
        for (int j = 0; j < 4; ++j) {
            int row = rbase + j;
            if (row < M) {
                float dv = dinv[row];
                short8v r;
#pragma unroll
                for (int ct = 0; ct < 8; ++ct) r[ct] = (short)f2bf_rne(dv * acc[rt][ct][j]);
                *(short8v*)(Cb + (size_t)row * 128 + lr * 8) = r;
            }
        }
    }
}

// ---------------- prop1: hidden' = dinv .* relu(dinv_v * (sum h'_c + h'_v) + b1), bf16 ----------------
// 16 lanes x 16B per row; 4 edges per iter; unroll x4.

__global__ __launch_bounds__(256) void k_prop1(const unsigned short* __restrict__ hb,
                                               const int* __restrict__ colv,
                                               const int* __restrict__ rowstart,
                                               const float* __restrict__ dinv,
                                               const float* __restrict__ bias,
                                               unsigned short* __restrict__ ob, int n) {
    int wid = (blockIdx.x * 256 + threadIdx.x) >> 6;
    if (wid >= n) return;
    int lane = threadIdx.x & 63;
    int q = lane >> 4, cl = lane & 15;
    int s = rowstart[wid], cnt = rowstart[wid + 1] - s;
    float a[8] = {0.f, 0.f, 0.f, 0.f, 0.f, 0.f, 0.f, 0.f};
    int i = 0;
    for (; i + 16 <= cnt; i += 16) {
        int c0 = colv[s + i + q];
        int c1 = colv[s + i + 4 + q];
        int c2 = colv[s + i + 8 + q];
        int c3 = colv[s + i + 12 + q];
        uint4 v0 = *(const uint4*)(hb + (size_t)c0 * 128 + cl * 8);
        uint4 v1 = *(const uint4*)(hb + (size_t)c1 * 128 + cl * 8);
        uint4 v2 = *(const uint4*)(hb + (size_t)c2 * 128 + cl * 8);
        uint4 v3 = *(const uint4*)(hb + (size_t)c3 * 128 + cl * 8);
        acc8(a, v0); acc8(a, v1); acc8(a, v2); acc8(a, v3);
    }
    for (; i + 4 <= cnt; i += 4) {
        int c = colv[s + i + q];
        uint4 v = *(const uint4*)(hb + (size_t)c * 128 + cl * 8);
        acc8(a, v);
    }
    if (q < cnt - i) {
        int c = colv[s + i + q];
        uint4 v = *(const uint4*)(hb + (size_t)c * 128 + cl * 8);
        acc8(a, v);
    }
#pragma unroll
    for (int k = 0; k < 8; ++k) {
        a[k] += __shfl_xor(a[k], 16);
        a[k] += __shfl_xor(a[k], 32);
    }
    if (q == 0) {
        uint4 vo = *(const uint4*)(hb + (size_t)wid * 128 + cl * 8);  // self-loop
        acc8(a, vo);
        float dv = dinv[wid];
        float4 b0 = *(const float4*)(bias + cl * 8);
        float4 b1v = *(const float4*)(bias + cl * 8 + 4);
        float bb[8] = {b0.x, b0.y, b0.z, b0.w, b1v.x, b1v.y, b1v.z, b1v.w};
        short8v r;
#pragma unroll
        for (int k = 0; k < 8; ++k) {
            float o = fmaxf(a[k] * dv + bb[k], 0.f) * dv;   // fold next-layer dinv
            r[k] = (short)f2bf_rne(o);
        }
        *(short8v*)(ob + (size_t)wid * 128 + cl * 8) = r;
    }
}

// ---------------- prop2: agg = dinv_v * (sum hidden'_c + hidden'_v), bf16 ----------------

__global__ __launch_bounds__(256) void k_prop2(const unsigned short* __restrict__ hb,
                                               const int* __restrict__ colv,
                                               const int* __restrict__ rowstart,
                                               const float* __restrict__ dinv,
                                               unsigned short* __restrict__ ob, int n) {
    int wid = (blockIdx.x * 256 + threadIdx.x) >> 6;
    if (wid >= n) return;
    int lane = threadIdx.x & 63;
    int q = lane >> 4, cl = lane & 15;
    int s = rowstart[wid], cnt = rowstart[wid + 1] - s;
    float a[8] = {0.f, 0.f, 0.f, 0.f, 0.f, 0.f, 0.f, 0.f};
    int i = 0;
    for (; i + 16 <= cnt; i += 16) {
        int c0 = colv[s + i + q];
        int c1 = colv[s + i + 4 + q];
        int c2 = colv[s + i + 8 + q];
        int c3 = colv[s + i + 12 + q];
        uint4 v0 = *(const uint4*)(hb + (size_t)c0 * 128 + cl * 8);
        uint4 v1 = *(const uint4*)(hb + (size_t)c1 * 128 + cl * 8);
        uint4 v2 = *(const uint4*)(hb + (size_t)c2 * 128 + cl * 8);
        uint4 v3 = *(const uint4*)(hb + (size_t)c3 * 128 + cl * 8);
        acc8(a, v0); acc8(a, v1); acc8(a, v2); acc8(a, v3);
    }
    for (; i + 4 <= cnt; i += 4) {
        int c = colv[s + i + q];
        uint4 v = *(const uint4*)(hb + (size_t)c * 128 + cl * 8);
        acc8(a, v);
    }
    if (q < cnt - i) {
        int c = colv[s + i + q];
        uint4 v = *(const uint4*)(hb + (size_t)c * 128 + cl * 8);
        acc8(a, v);
    }
#pragma unroll
    for (int k = 0; k < 8; ++k) {
        a[k] += __shfl_xor(a[k], 16);
        a[k] += __shfl_xor(a[k], 32);
    }
    if (q == 0) {
        uint4 vo = *(const uint4*)(hb + (size_t)wid * 128 + cl * 8);
        acc8(a, vo);
        float dv = dinv[wid];
        short8v r;
#pragma unroll
        for (int k = 0; k < 8; ++k) r[k] = (short)f2bf_rne(a[k] * dv);
        *(short8v*)(ob + (size_t)wid * 128 + cl * 8) = r;
    }
}

// ---------------- GEMM2 + epilogue: [mu|ls] = agg @ [Wmu|Wls] + b ; z = mu + eps*exp(ls) ----------------
// A bf16 (exact), B split hi/lo (2 MFMA). Lane lr<8 owns mu channels lr*8+ct; lr>=8 -> ls.

__global__ __launch_bounds__(256) void k_gemm2z(const unsigned short* __restrict__ Ab,
                                                const unsigned short* __restrict__ Bth,
                                                const unsigned short* __restrict__ Btl,
                                                const float* __restrict__ bmu,
                                                const float* __restrict__ bls,
                                                const float* __restrict__ eps,
                                                float* __restrict__ zout,
                                                float* __restrict__ muout,
                                                float* __restrict__ lsout, int M) {
    const int K = 128;
    const int tid = threadIdx.x;
    const int wv = tid >> 6, l = tid & 63;
    const int lr = l & 15, lk = (l >> 4) * 8;
    const int row0 = blockIdx.x * 128 + wv * 32;

    f32x4 acc[2][8];
#pragma unroll
    for (int rt = 0; rt < 2; ++rt)
#pragma unroll
        for (int ct = 0; ct < 8; ++ct) acc[rt][ct] = (f32x4){0.f, 0.f, 0.f, 0.f};

    int r0g = row0 + lr, r1g = row0 + 16 + lr;
    const unsigned short* a0p = Ab + (size_t)(r0g < M ? r0g : 0) * K;
    const unsigned short* a1p = Ab + (size_t)(r1g < M ? r1g : 0) * K;

    for (int k0 = 0; k0 < K; k0 += 32) {
        short8v a0 = *(const short8v*)(a0p + k0 + lk);
        short8v a1 = *(const short8v*)(a1p + k0 + lk);
#pragma unroll
        for (int ct = 0; ct < 8; ++ct) {
            const size_t bo = (size_t)(ct * 16 + lr) * K + k0 + lk;
            short8v bh = *(const short8v*)(Bth + bo);
            short8v bl = *(const short8v*)(Btl + bo);
            acc[0][ct] = __builtin_amdgcn_mfma_f32_16x16x32_bf16(a0, bh, acc[0][ct], 0, 0, 0);
            acc[0][ct] = __builtin_amdgcn_mfma_f32_16x16x32_bf16(a0, bl, acc[0][ct], 0, 0, 0);
            acc[1][ct] = __builtin_amdgcn_mfma_f32_16x16x32_bf16(a1, bh, acc[1][ct], 0, 0, 0);
            acc[1][ct] = __builtin_amdgcn_mfma_f32_16x16x32_bf16(a1, bl, acc[1][ct], 0, 0, 0);
        }
    }

    const bool isMu = (lr < 8);
    float bb[8];
#pragma unroll
    for (int ct = 0; ct < 8; ++ct)
        bb[ct] = isMu ? bmu[lr * 8 + ct] : bls[(lr - 8) * 8 + ct];

#pragma unroll
    for (int rt = 0; rt < 2; ++rt) {
        int rbase = row0 + rt * 16 + ((l >> 4) << 2);
#pragma unroll
        for (int j = 0; j < 4; ++j) {
            int row = rbase + j;
            float val[8], ex[8], exs[8];
#pragma unroll
            for (int ct = 0; ct < 8; ++ct) {
                val[ct] = acc[rt][ct][j] + bb[ct];
                ex[ct] = __expf(val[ct]);
            }
#pragma unroll
            for (int ct = 0; ct < 8; ++ct) exs[ct] = __shfl(ex[ct], l + 8);  // ls partner
            if (row < M) {
                if (isMu) {
                    size_t o = (size_t)row * 64 + lr * 8;
                    float4 e0 = *(const float4*)(eps + o);
                    float4 e1 = *(const float4*)(eps + o + 4);
                    float epv[8] = {e0.x, e0.y, e0.z, e0.w, e1.x, e1.y, e1.z, e1.w};
                    float z[8];
#pragma unroll
                    for (int ct = 0; ct < 8; ++ct) z[ct] = val[ct] + epv[ct] * exs[ct];
                    *(float4*)(zout + o)     = make_float4(z[0], z[1], z[2], z[3]);
                    *(float4*)(zout + o + 4) = make_float4(z[4], z[5], z[6], z[7]);
                    *(float4*)(muout + o)     = make_float4(val[0], val[1], val[2], val[3]);
                    *(float4*)(muout + o + 4) = make_float4(val[4], val[5], val[6], val[7]);
                } else {
                    size_t o = (size_t)row * 64 + (lr - 8) * 8;
                    *(float4*)(lsout + o)     = make_float4(val[0], val[1], val[2], val[3]);
                    *(float4*)(lsout + o + 4) = make_float4(val[4], val[5], val[6], val[7]);
                }
            }
        }
    }
}

// ---------------- launch ----------------

extern "C" void kernel_launch(void* const* d_in, const int* in_sizes, int n_in,
                              void* d_out, int out_size, void* d_ws, size_t ws_size,
                              hipStream_t stream) {
    const float* x   = (const float*)d_in[0];
    const int*   ei  = (const int*)d_in[1];
    const float* W1  = (const float*)d_in[2];
    const float* b1  = (const float*)d_in[3];
    const float* Wmu = (const float*)d_in[4];
    const float* bmu = (const float*)d_in[5];
    const float* Wls = (const float*)d_in[6];
    const float* bls = (const float*)d_in[7];
    const float* eps = (const float*)d_in[8];

    const int n = in_sizes[0] / 256;   // 100000
    const int E = in_sizes[1] / 2;     // 1600000
    const int* srcv = ei;
    const int* dstv = ei + E;
    const int nbuck = (n + 511) >> BSHIFT;

    char* w = (char*)d_ws;
    auto alloc = [&](size_t bytes) -> char* {
        char* p = w;
        w += (bytes + 255) & ~(size_t)255;
        return p;
    };
    float* dinv     = (float*)alloc((size_t)n * 4);
    int*   rowstart = (int*)alloc((size_t)(n + 1) * 4);
    int*   gcnt     = (int*)alloc((size_t)NBUCK_MAX * 4);
    int*   bstart   = (int*)alloc((size_t)(NBUCK_MAX + 1) * 4);
    int*   bcur     = (int*)alloc((size_t)NBUCK_MAX * 4);
    int*   colv     = (int*)alloc((size_t)E * 4);
    unsigned long long* ebuf = (unsigned long long*)alloc((size_t)E * 8);
    unsigned short* B1h = (unsigned short*)alloc(128 * 256 * 2);
    unsigned short* B1l = (unsigned short*)alloc(128 * 256 * 2);
    unsigned short* B2h = (unsigned short*)alloc(128 * 128 * 2);
    unsigned short* B2l = (unsigned short*)alloc(128 * 128 * 2);
    unsigned short* hbuf = (unsigned short*)alloc((size_t)n * 128 * 2);  // h', then agg
    unsigned short* hid  = (unsigned short*)alloc((size_t)n * 128 * 2);  // hidden'

    const int ecb = (E + 4095) / 4096;

    hipMemsetAsync(gcnt, 0, NBUCK_MAX * 4, stream);
    k_hist<<<ecb, 256, 0, stream>>>(dstv, gcnt, E);
    k_scanb<<<1, 256, 0, stream>>>(gcnt, bstart, bcur, nbuck, E);
    k_scatb<<<ecb, 256, 0, stream>>>(srcv, dstv, bcur, ebuf, E);
    k_bsort<<<nbuck, 512, 0, stream>>>(ebuf, bstart, colv, rowstart, dinv, n, nbuck, E);
    k_prepB<<<128, 256, 0, stream>>>(W1, Wmu, Wls, B1h, B1l, B2h, B2l);

    k_gemm1<<<(n + 127) / 128, 256, 0, stream>>>(x, B1h, B1l, dinv, hbuf, n);
    k_prop1<<<(n + 3) / 4, 256, 0, stream>>>(hbuf, colv, rowstart, dinv, b1, hid, n);
    k_prop2<<<(n + 3) / 4, 256, 0, stream>>>(hid, colv, rowstart, dinv, hbuf, n);

    float* zout  = (float*)d_out;
    float* muout = zout + (size_t)n * 64;
    float* lsout = muout + (size_t)n * 64;
    k_gemm2z<<<(n + 127) / 128, 256, 0, stream>>>(hbuf, B2h, B2l, bmu, bls, eps,
                                                  zout, muout, lsout, n);
}